// Round 2
// baseline (143.193 us; speedup 1.0000x reference)
//
#include <hip/hip_runtime.h>
#include <math.h>

#define EPS 1e-8f
#define SCB 256      // scatter blocks (reservation-based counting sort)
#define NG  256      // gemm1 blocks
#define CAP 768      // per-disease slab capacity (lambda=488, 12.7 sigma headroom)

// ---------------------------------------------------------------------------
// K0: wave-per-row norms, no LDS / no syncthreads.
//   blocks [0, S/4): wave w -> s = bid*4+w : rinv[s] = 1/(||S_s||+eps)
//   blocks [S/4, S/4+B/4): wave w -> b : Hs[b,:] = H[b,:]/(||H_b||+eps),
//                                         gscale[b] = 0.005*||G_b||
//   last block: zero cursor[0..D)
// ---------------------------------------------------------------------------
__global__ __launch_bounds__(256) void k_norms(
        const float* __restrict__ Sg, const float* __restrict__ Hg,
        const float* __restrict__ Gg, float* __restrict__ rinv,
        float* __restrict__ Hs, float* __restrict__ gscale,
        int* __restrict__ cursor, int Srows, int Fdim, int Bdim, int Dd) {
    int bid = blockIdx.x;
    int tid = threadIdx.x;
    int lane = tid & 63, w = tid >> 6;
    int ns4 = Srows >> 2;                  // 2048
    int nf4 = Fdim >> 2;                   // 128 float4 per row

    if (bid < ns4) {
        int s = bid * 4 + w;
        const float4* p = (const float4*)(Sg + (size_t)s * Fdim);
        float4 a = p[lane], c = p[lane + 64];
        float acc = a.x * a.x + a.y * a.y + a.z * a.z + a.w * a.w
                  + c.x * c.x + c.y * c.y + c.z * c.z + c.w * c.w;
        #pragma unroll
        for (int off = 32; off; off >>= 1) acc += __shfl_xor(acc, off, 64);
        if (lane == 0) rinv[s] = 1.0f / (sqrtf(acc) + EPS);
        (void)nf4;
    } else if (bid < ns4 + (Bdim >> 2)) {
        int b = (bid - ns4) * 4 + w;
        const float4* ph = (const float4*)(Hg + (size_t)b * Fdim);
        const float4* pg = (const float4*)(Gg + (size_t)b * Fdim);
        float4 h0 = ph[lane], h1 = ph[lane + 64];
        float4 g0 = pg[lane], g1 = pg[lane + 64];
        float ah = h0.x * h0.x + h0.y * h0.y + h0.z * h0.z + h0.w * h0.w
                 + h1.x * h1.x + h1.y * h1.y + h1.z * h1.z + h1.w * h1.w;
        float ag = g0.x * g0.x + g0.y * g0.y + g0.z * g0.z + g0.w * g0.w
                 + g1.x * g1.x + g1.y * g1.y + g1.z * g1.z + g1.w * g1.w;
        #pragma unroll
        for (int off = 32; off; off >>= 1) {
            ah += __shfl_xor(ah, off, 64);
            ag += __shfl_xor(ag, off, 64);
        }
        float hn = 1.0f / (sqrtf(ah) + EPS);
        if (lane == 0) gscale[b] = 0.005f * sqrtf(ag);   // 0.01 eta * 0.5 rescale
        float4* dst = (float4*)(Hs + (size_t)b * Fdim);
        float4 o0, o1;
        o0.x = h0.x * hn; o0.y = h0.y * hn; o0.z = h0.z * hn; o0.w = h0.w * hn;
        o1.x = h1.x * hn; o1.y = h1.y * hn; o1.z = h1.z * hn; o1.w = h1.w * hn;
        dst[lane] = o0; dst[lane + 64] = o1;
    } else {
        for (int i = tid; i < Dd; i += 256) cursor[i] = 0;
    }
}

// ---------------------------------------------------------------------------
// K1: blocks [0,NG): GEMM1  Pt[s][b] = rinv[s] * sum_k Hs[b,k]*Sg[s,k]
//       32 s-rows x 64 b per block. Lane owns b: Hs staged [b][k] rows so
//       each lane b128-reads its OWN row (4 k per read); Sg rows are
//       wave-uniform b128 broadcasts. 32 FMA per 4k per wave -> VALU-bound.
//     blocks [NG, NG+SCB): reservation scatter — LDS histogram, one
//       atomicAdd(&cursor[d], cnt) per present bin reserves a slab range,
//       edges written to sorted[d*CAP + pos]. No global scan needed.
// ---------------------------------------------------------------------------
__global__ __launch_bounds__(256) void k_g1scat(
        const float* __restrict__ Hs, const float* __restrict__ Sg,
        const float* __restrict__ rinv, float* __restrict__ Pt,
        const int* __restrict__ ed, const int* __restrict__ es,
        const float* __restrict__ ew, int* __restrict__ cursor,
        int2* __restrict__ sorted, int Srows, int Fdim, int E, int Dd) {
    __shared__ float smem[64 * 68 + 32 * 68];      // 26.1 KB (union w/ scatter)
    int id = blockIdx.x;
    int tid = threadIdx.x;

    if (id < NG) {
        float (*Hl)[68] = (float(*)[68])smem;            // [b][k] padded
        float (*Sl)[68] = (float(*)[68])(smem + 64 * 68);// [s][k] padded
        int lane = tid & 63, w = tid >> 6;
        int s0 = id * 32;

        float acc[8];
        #pragma unroll
        for (int i = 0; i < 8; i++) acc[i] = 0.f;

        for (int kt = 0; kt < Fdim; kt += 64) {
            #pragma unroll
            for (int i = 0; i < 4; i++) {                // 64b x 64k tile
                int idx = tid + i * 256;                 // 0..1023 float4s
                int c = idx & 15, r = idx >> 4;
                *(float4*)&Hl[r][c * 4] =
                    *(const float4*)&Hs[(size_t)r * Fdim + kt + c * 4];
            }
            #pragma unroll
            for (int i = 0; i < 2; i++) {                // 32s x 64k tile
                int idx = tid + i * 256;                 // 0..511 float4s
                int c = idx & 15, r = idx >> 4;
                *(float4*)&Sl[r][c * 4] =
                    *(const float4*)&Sg[(size_t)(s0 + r) * Fdim + kt + c * 4];
            }
            __syncthreads();
            #pragma unroll
            for (int kk = 0; kk < 16; kk++) {
                float4 hv = *(float4*)&Hl[lane][kk * 4];
                #pragma unroll
                for (int si = 0; si < 8; si++) {
                    float4 sv = *(float4*)&Sl[w * 8 + si][kk * 4];
                    acc[si] += sv.x * hv.x + sv.y * hv.y
                             + sv.z * hv.z + sv.w * hv.w;
                }
            }
            __syncthreads();
        }
        #pragma unroll
        for (int si = 0; si < 8; si++) {
            int s = s0 + w * 8 + si;
            Pt[(size_t)s * 64 + lane] = acc[si] * rinv[s];
        }
    } else {
        int* cnt = (int*)smem;                           // 1024 ints
        int h = id - NG;
        for (int i = tid; i < Dd; i += 256) cnt[i] = 0;
        __syncthreads();
        int chunk = (E + SCB - 1) / SCB;
        int e0 = h * chunk;
        int e1 = min(E, e0 + chunk);
        int myd[8], mys[8], myr[8];
        float myw[8];
        #pragma unroll
        for (int i = 0; i < 8; i++) {
            int e = e0 + tid + i * 256;
            myd[i] = -1;
            if (e < e1) {
                myd[i] = ed[e]; mys[i] = es[e]; myw[i] = ew[e];
                myr[i] = atomicAdd(&cnt[myd[i]], 1);
            }
        }
        __syncthreads();
        for (int d = tid; d < Dd; d += 256) {
            int c = cnt[d];
            if (c) cnt[d] = atomicAdd(&cursor[d], c);    // slab base for block
        }
        __syncthreads();
        #pragma unroll
        for (int i = 0; i < 8; i++) {
            if (myd[i] >= 0) {
                int pos = cnt[myd[i]] + myr[i];
                sorted[(size_t)myd[i] * CAP + pos] =
                    make_int2(mys[i], __float_as_int(myw[i]));
            }
        }
    }
}

// ---------------------------------------------------------------------------
// K2: gather — block d: out[b,d] = gscale[b]*(sum_e ew*Pt[es][b] + sum_e ew)
//     cursor[d] holds the final bucket count; slab base is d*CAP.
//     4 waves split the bucket; lane = b; Pt columns are 256B coalesced
//     L2-resident reads. Register accumulation, LDS combine, direct write.
// ---------------------------------------------------------------------------
__global__ __launch_bounds__(256) void k_gather(
        const int2* __restrict__ sorted, const float* __restrict__ Pt,
        const int* __restrict__ cursor, const float* __restrict__ gscale,
        float* __restrict__ out, int Dd) {
    __shared__ float sacc[4][64];
    __shared__ float scs[4];
    int d = blockIdx.x;
    int tid = threadIdx.x;
    int lane = tid & 63, w = tid >> 6;
    int cnt = cursor[d];
    const int2* sp = sorted + (size_t)d * CAP;
    float acc = 0.f, cs = 0.f;
    #pragma unroll 8
    for (int i = w; i < cnt; i += 4) {
        int2 p = sp[i];
        float wt = __int_as_float(p.y);
        acc += wt * Pt[(size_t)p.x * 64 + lane];
        cs += wt;
    }
    sacc[w][lane] = acc;
    if (lane == 0) scs[w] = cs;
    __syncthreads();
    if (tid < 64) {
        float a = sacc[0][tid] + sacc[1][tid] + sacc[2][tid] + sacc[3][tid]
                + scs[0] + scs[1] + scs[2] + scs[3];
        out[(size_t)tid * Dd + d] = gscale[tid] * a;
    }
}

extern "C" void kernel_launch(void* const* d_in, const int* in_sizes, int n_in,
                              void* d_out, int out_size, void* d_ws, size_t ws_size,
                              hipStream_t stream) {
    const float* H  = (const float*)d_in[0];
    const float* G  = (const float*)d_in[1];
    const float* Sg = (const float*)d_in[2];
    const float* ew = (const float*)d_in[3];
    const int*   ed = (const int*)d_in[4];
    const int*   es = (const int*)d_in[5];

    const int B = 64;
    const int F = in_sizes[0] / B;        // 512
    const int S = in_sizes[2] / F;        // 8192
    const int E = in_sizes[3];            // 500000
    const int D = out_size / B;           // 1024
    float* out = (float*)d_out;

    // workspace layout (float units; every buffer fully written before read)
    float* ws = (float*)d_ws;
    size_t off = 0;
    float* rinv   = ws + off; off += (size_t)S;            // 8192
    float* Hs     = ws + off; off += (size_t)B * F;        // 32768
    float* gscale = ws + off; off += 256;
    float* Pt     = ws + off; off += (size_t)S * B;        // 524288 (2 MB)
    int*   cursor = (int*)(ws + off); off += (size_t)D;    // 4 KB
    int2*  sorted = (int2*)(ws + off); off += 2 * (size_t)D * CAP;  // 6.3 MB

    // K0: wave-per-row norms + cursor zero
    k_norms<<<S / 4 + B / 4 + 1, 256, 0, stream>>>(Sg, H, G, rinv, Hs, gscale,
                                                   cursor, S, F, B, D);
    // K1: GEMM1 (NG blocks, VALU-bound) || reservation scatter (SCB blocks)
    k_g1scat<<<NG + SCB, 256, 0, stream>>>(Hs, Sg, rinv, Pt, ed, es, ew,
                                           cursor, sorted, S, F, E, D);
    // K2: per-disease register gather -> out
    k_gather<<<D, 256, 0, stream>>>(sorted, Pt, cursor, gscale, out, D);
}

// Round 3
// 118.235 us; speedup vs baseline: 1.2111x; 1.2111x over previous
//
#include <hip/hip_runtime.h>
#include <math.h>

#define EPS 1e-8f
#define SCB 256      // scatter blocks (reservation-based counting sort)
#define NG1 128      // gemm1 blocks (4 waves x 16 s-rows = 64 s each)
#define CAP 768      // per-disease slab capacity (lambda=488, 12.7 sigma headroom)

typedef __attribute__((ext_vector_type(8))) __bf16 bf16x8;
typedef __attribute__((ext_vector_type(4))) float f32x4;

// float -> bf16 (round to nearest even), bit-level
__device__ __forceinline__ unsigned short f2bf(float x) {
    unsigned int u = __float_as_uint(x);
    u += 0x7FFFu + ((u >> 16) & 1u);
    return (unsigned short)(u >> 16);
}
__device__ __forceinline__ unsigned int pack2(float lo, float hi) {
    return (unsigned int)f2bf(lo) | ((unsigned int)f2bf(hi) << 16);
}

// ---------------------------------------------------------------------------
// K0: wave-per-row norms folded into bf16 conversion. No LDS, no syncthreads.
//   blocks [0, S/4): wave w -> s: Sgb[s,:] = bf16(Sg[s,:] / (||S_s||+eps))
//   blocks [S/4, S/4+16): wave w -> b: Hsb[b,:] = bf16(H[b,:]/(||H_b||+eps)),
//                                      gscale[b] = 0.005*||G_b||
//   last block: zero cursor[0..D)
// ---------------------------------------------------------------------------
__global__ __launch_bounds__(256) void k_norms(
        const float* __restrict__ Sg, const float* __restrict__ Hg,
        const float* __restrict__ Gg, unsigned short* __restrict__ Sgb,
        unsigned short* __restrict__ Hsb, float* __restrict__ gscale,
        int* __restrict__ cursor, int Srows, int Fdim, int Bdim, int Dd) {
    int bid = blockIdx.x;
    int tid = threadIdx.x;
    int lane = tid & 63, w = tid >> 6;
    int ns4 = Srows >> 2;                  // 2048

    if (bid < ns4) {
        int s = bid * 4 + w;
        const float4* p = (const float4*)(Sg + (size_t)s * Fdim);
        float4 a = p[2 * lane], c = p[2 * lane + 1];     // cols 8l..8l+7
        float acc = a.x * a.x + a.y * a.y + a.z * a.z + a.w * a.w
                  + c.x * c.x + c.y * c.y + c.z * c.z + c.w * c.w;
        #pragma unroll
        for (int off = 32; off; off >>= 1) acc += __shfl_xor(acc, off, 64);
        float rv = 1.0f / (sqrtf(acc) + EPS);
        uint4 o;
        o.x = pack2(a.x * rv, a.y * rv);
        o.y = pack2(a.z * rv, a.w * rv);
        o.z = pack2(c.x * rv, c.y * rv);
        o.w = pack2(c.z * rv, c.w * rv);
        *(uint4*)(Sgb + (size_t)s * Fdim + lane * 8) = o;
    } else if (bid < ns4 + (Bdim >> 2)) {
        int b = (bid - ns4) * 4 + w;
        const float4* ph = (const float4*)(Hg + (size_t)b * Fdim);
        const float4* pg = (const float4*)(Gg + (size_t)b * Fdim);
        float4 h0 = ph[2 * lane], h1 = ph[2 * lane + 1];
        float4 g0 = pg[2 * lane], g1 = pg[2 * lane + 1];
        float ah = h0.x * h0.x + h0.y * h0.y + h0.z * h0.z + h0.w * h0.w
                 + h1.x * h1.x + h1.y * h1.y + h1.z * h1.z + h1.w * h1.w;
        float ag = g0.x * g0.x + g0.y * g0.y + g0.z * g0.z + g0.w * g0.w
                 + g1.x * g1.x + g1.y * g1.y + g1.z * g1.z + g1.w * g1.w;
        #pragma unroll
        for (int off = 32; off; off >>= 1) {
            ah += __shfl_xor(ah, off, 64);
            ag += __shfl_xor(ag, off, 64);
        }
        float hn = 1.0f / (sqrtf(ah) + EPS);
        if (lane == 0) gscale[b] = 0.005f * sqrtf(ag);   // 0.01 eta * 0.5 rescale
        uint4 o;
        o.x = pack2(h0.x * hn, h0.y * hn);
        o.y = pack2(h0.z * hn, h0.w * hn);
        o.z = pack2(h1.x * hn, h1.y * hn);
        o.w = pack2(h1.z * hn, h1.w * hn);
        *(uint4*)(Hsb + (size_t)b * Fdim + lane * 8) = o;
    } else {
        for (int i = tid; i < Dd; i += 256) cursor[i] = 0;
    }
}

// ---------------------------------------------------------------------------
// K1: blocks [0,NG1): MFMA GEMM1  Pt[s][b] = sum_k Snb[s][k]*Hnb[b][k]
//       (= cosine; norms pre-folded in bf16 operands). Per wave: 16 s-rows,
//       64 b via 4 n-tiles of v_mfma_f32_16x16x32_bf16. Fragments are 16B
//       contiguous-k loads DIRECT FROM GLOBAL: A streams Sgb (coalesced,
//       16 rows x 64B per wave-load); B re-reads the 64KB Hsb (L1/L2-hot).
//       Zero LDS, zero syncthreads -> LDS pipe idle (round-2 bottleneck).
//     blocks [NG1, NG1+SCB): reservation scatter — LDS histogram, one
//       atomicAdd(&cursor[d], cnt) per present bin reserves a slab range,
//       edges written to sorted[d*CAP + pos].
// ---------------------------------------------------------------------------
__global__ __launch_bounds__(256) void k_g1scat(
        const unsigned short* __restrict__ Sgb,
        const unsigned short* __restrict__ Hsb, float* __restrict__ Pt,
        const int* __restrict__ ed, const int* __restrict__ es,
        const float* __restrict__ ew, int* __restrict__ cursor,
        int2* __restrict__ sorted, int Srows, int Fdim, int E, int Dd) {
    __shared__ int cnt[1024];
    int id = blockIdx.x;
    int tid = threadIdx.x;

    if (id < NG1) {
        int lane = tid & 63, w = tid >> 6;
        int r16 = lane & 15, q = lane >> 4;
        int s0 = (id * 4 + w) * 16;
        // bf16x8 units: row stride = Fdim/8 = 64, k-step stride = 4
        const bf16x8* Ap = (const bf16x8*)(Sgb + (size_t)(s0 + r16) * Fdim) + q;
        const bf16x8* Bp = (const bf16x8*)(Hsb + (size_t)r16 * Fdim) + q;

        f32x4 acc0 = {0.f, 0.f, 0.f, 0.f};
        f32x4 acc1 = {0.f, 0.f, 0.f, 0.f};
        f32x4 acc2 = {0.f, 0.f, 0.f, 0.f};
        f32x4 acc3 = {0.f, 0.f, 0.f, 0.f};

        #pragma unroll 4
        for (int kt = 0; kt < 16; kt++) {          // 16 k-steps of K=32
            bf16x8 a  = Ap[kt * 4];
            bf16x8 b0 = Bp[kt * 4];
            bf16x8 b1 = Bp[kt * 4 + 16 * 64];      // b-rows 16..31
            bf16x8 b2 = Bp[kt * 4 + 32 * 64];      // b-rows 32..47
            bf16x8 b3 = Bp[kt * 4 + 48 * 64];      // b-rows 48..63
            acc0 = __builtin_amdgcn_mfma_f32_16x16x32_bf16(a, b0, acc0, 0, 0, 0);
            acc1 = __builtin_amdgcn_mfma_f32_16x16x32_bf16(a, b1, acc1, 0, 0, 0);
            acc2 = __builtin_amdgcn_mfma_f32_16x16x32_bf16(a, b2, acc2, 0, 0, 0);
            acc3 = __builtin_amdgcn_mfma_f32_16x16x32_bf16(a, b3, acc3, 0, 0, 0);
        }
        // C/D layout (m89, verified): col = lane&15, row = (lane>>4)*4 + reg
        #pragma unroll
        for (int r = 0; r < 4; r++) {
            int s = s0 + q * 4 + r;
            float* row = Pt + (size_t)s * 64 + r16;
            row[0]  = acc0[r];
            row[16] = acc1[r];
            row[32] = acc2[r];
            row[48] = acc3[r];
        }
    } else {
        int h = id - NG1;
        for (int i = tid; i < Dd; i += 256) cnt[i] = 0;
        __syncthreads();
        int chunk = (E + SCB - 1) / SCB;
        int e0 = h * chunk;
        int e1 = min(E, e0 + chunk);
        int myd[8], mys[8], myr[8];
        float myw[8];
        #pragma unroll
        for (int i = 0; i < 8; i++) {
            int e = e0 + tid + i * 256;
            myd[i] = -1;
            if (e < e1) {
                myd[i] = ed[e]; mys[i] = es[e]; myw[i] = ew[e];
                myr[i] = atomicAdd(&cnt[myd[i]], 1);
            }
        }
        __syncthreads();
        for (int d = tid; d < Dd; d += 256) {
            int c = cnt[d];
            if (c) cnt[d] = atomicAdd(&cursor[d], c);    // slab base for block
        }
        __syncthreads();
        #pragma unroll
        for (int i = 0; i < 8; i++) {
            if (myd[i] >= 0) {
                int pos = cnt[myd[i]] + myr[i];
                sorted[(size_t)myd[i] * CAP + pos] =
                    make_int2(mys[i], __float_as_int(myw[i]));
            }
        }
    }
}

// ---------------------------------------------------------------------------
// K2: gather — block d: out[b,d] = gscale[b]*(sum_e ew*Pt[es][b] + sum_e ew)
//     cursor[d] holds the final bucket count; slab base is d*CAP.
//     4 waves split the bucket; lane = b; Pt columns are 256B coalesced
//     L2-resident reads. Register accumulation, LDS combine, direct write.
// ---------------------------------------------------------------------------
__global__ __launch_bounds__(256) void k_gather(
        const int2* __restrict__ sorted, const float* __restrict__ Pt,
        const int* __restrict__ cursor, const float* __restrict__ gscale,
        float* __restrict__ out, int Dd) {
    __shared__ float sacc[4][64];
    __shared__ float scs[4];
    int d = blockIdx.x;
    int tid = threadIdx.x;
    int lane = tid & 63, w = tid >> 6;
    int cnt = cursor[d];
    const int2* sp = sorted + (size_t)d * CAP;
    float acc = 0.f, cs = 0.f;
    #pragma unroll 8
    for (int i = w; i < cnt; i += 4) {
        int2 p = sp[i];
        float wt = __int_as_float(p.y);
        acc += wt * Pt[(size_t)p.x * 64 + lane];
        cs += wt;
    }
    sacc[w][lane] = acc;
    if (lane == 0) scs[w] = cs;
    __syncthreads();
    if (tid < 64) {
        float a = sacc[0][tid] + sacc[1][tid] + sacc[2][tid] + sacc[3][tid]
                + scs[0] + scs[1] + scs[2] + scs[3];
        out[(size_t)tid * Dd + d] = gscale[tid] * a;
    }
}

extern "C" void kernel_launch(void* const* d_in, const int* in_sizes, int n_in,
                              void* d_out, int out_size, void* d_ws, size_t ws_size,
                              hipStream_t stream) {
    const float* H  = (const float*)d_in[0];
    const float* G  = (const float*)d_in[1];
    const float* Sg = (const float*)d_in[2];
    const float* ew = (const float*)d_in[3];
    const int*   ed = (const int*)d_in[4];
    const int*   es = (const int*)d_in[5];

    const int B = 64;
    const int F = in_sizes[0] / B;        // 512
    const int S = in_sizes[2] / F;        // 8192
    const int E = in_sizes[3];            // 500000
    const int D = out_size / B;           // 1024
    float* out = (float*)d_out;

    // workspace layout (float units; every buffer fully written before read)
    float* ws = (float*)d_ws;
    size_t off = 0;
    unsigned short* Sgb = (unsigned short*)(ws + off); off += (size_t)S * F / 2;  // 8.4 MB
    unsigned short* Hsb = (unsigned short*)(ws + off); off += (size_t)B * F / 2;  // 64 KB
    float* gscale = ws + off; off += 256;
    float* Pt     = ws + off; off += (size_t)S * B;        // 2 MB
    int*   cursor = (int*)(ws + off); off += (size_t)D;    // 4 KB
    int2*  sorted = (int2*)(ws + off); off += 2 * (size_t)D * CAP;  // 6.3 MB

    // K0: norms folded into bf16 conversion + cursor zero
    k_norms<<<S / 4 + B / 4 + 1, 256, 0, stream>>>(Sg, H, G, Sgb, Hsb, gscale,
                                                   cursor, S, F, B, D);
    // K1: MFMA GEMM1 (NG1 blocks, no LDS) || reservation scatter (SCB blocks)
    k_g1scat<<<NG1 + SCB, 256, 0, stream>>>(Sgb, Hsb, Pt, ed, es, ew,
                                            cursor, sorted, S, F, E, D);
    // K2: per-disease register gather -> out
    k_gather<<<D, 256, 0, stream>>>(sorted, Pt, cursor, gscale, out, D);
}